// Round 2
// baseline (631.093 us; speedup 1.0000x reference)
//
#include <hip/hip_runtime.h>

// Problem constants
#define ARW_N_NODES   100000
#define ARW_N_EDGES   3200000
#define ARW_N_WALKERS 400000
#define ARW_WLEN      8
#define ARW_LOUT      7
#define ARW_ROW_LEN   6000000           // N_EDGES + N_WALKERS*LOUT
#define ARW_OUT_ELEMS 18000000          // float32 output elements

// CSR build: atomic scatter + per-row rank-by-e (stable order == rank of original
// edge index within row; e values are globally distinct so rank is exact).
//
// Scratch inside d_out (18M floats = 72MB), int32 view; staged lifetimes
// (everything in [0,9M) and [12M,15.2M) is dead before walk/asm overwrite it):
//   deg  @ [0, 100000)          atomic degree counters (zeroed first)
//   cnt  @ [150000, 250000)     scatter cursors, init = rowptr
//   tot  @ [300000, +98)        per-chunk degree sums
//   cb2  @ [300200, +98)        chunk exclusive bases
//   pd   @ [1400000, 1500000)   packed (rowptr<<10 | deg)
//   ec   @ [2600000, 9000000)   int2 (e, col) per slot, unordered within row
//   col_s@ [12000000, 15200000) final stable CSR cols (weights region; asm last)
// walk writes float targets @ [9200000, 12000000). asm (last) overwrites all scratch.
#define ARW_DEG   0
#define ARW_CNT   150000
#define ARW_TOT   300000
#define ARW_CB2   300200
#define ARW_PD    1400000
#define ARW_EC    2600000
#define ARW_COLS  12000000

#define ARW_NC2   98                   // 98 chunks of 1024 cover 100000 nodes

__global__ void AddRandomWalkEdge_16896401342869_kernel() {}

// ---------- 1. zero degree counters ----------
__global__ __launch_bounds__(1024) void arw16896_zero(int* __restrict__ s) {
    int i = blockIdx.x * 1024 + threadIdx.x;
    if (i < ARW_N_NODES) s[ARW_DEG + i] = 0;
}

// ---------- 2. degree histogram (global atomics, 400KB table L2-resident) ----------
__global__ __launch_bounds__(256) void arw16896_deg(const int* __restrict__ row,
                                                    int* __restrict__ s) {
    int e = blockIdx.x * 256 + threadIdx.x;      // grid covers exactly N_EDGES
    atomicAdd(&s[ARW_DEG + row[e]], 1);
}

// ---------- 3a. per-chunk totals ----------
__global__ __launch_bounds__(1024) void arw16896_tot(int* __restrict__ s) {
    __shared__ int wsum[16];
    int j = blockIdx.x, tid = threadIdx.x, lane = tid & 63, wid = tid >> 6;
    int idx = j * 1024 + tid;
    int a = (idx < ARW_N_NODES) ? s[ARW_DEG + idx] : 0;
    #pragma unroll
    for (int off = 32; off > 0; off >>= 1) a += __shfl_down(a, off, 64);
    if (lane == 0) wsum[wid] = a;
    __syncthreads();
    if (tid == 0) {
        int t = 0;
        #pragma unroll
        for (int w = 0; w < 16; w++) t += wsum[w];
        s[ARW_TOT + j] = t;
    }
}

// ---------- 3b. exclusive scan of 98 chunk totals (1 block) ----------
__global__ __launch_bounds__(128) void arw16896_base(int* __restrict__ s) {
    __shared__ int sm[128];
    int tid = threadIdx.x;
    int v = (tid < ARW_NC2) ? s[ARW_TOT + tid] : 0;
    sm[tid] = v;
    __syncthreads();
    for (int off = 1; off < 128; off <<= 1) {
        int x = 0;
        if (tid >= off) x = sm[tid - off];
        __syncthreads();
        sm[tid] += x;
        __syncthreads();
    }
    if (tid < ARW_NC2) s[ARW_CB2 + tid] = sm[tid] - v;
}

// ---------- 3c. rowptr: chunk-local scan + base; emit pd and scatter cursors ----------
__global__ __launch_bounds__(1024) void arw16896_ptr(int* __restrict__ s) {
    __shared__ int wsum[16];
    int j = blockIdx.x, tid = threadIdx.x, lane = tid & 63, wid = tid >> 6;
    int idx = j * 1024 + tid;
    int v = (idx < ARW_N_NODES) ? s[ARW_DEG + idx] : 0;
    int sv = v;
    #pragma unroll
    for (int off = 1; off < 64; off <<= 1) {
        int x = __shfl_up(sv, off, 64);
        if (lane >= off) sv += x;
    }
    if (lane == 63) wsum[wid] = sv;
    __syncthreads();
    int pre = 0;
    for (int w = 0; w < wid; w++) pre += wsum[w];
    if (idx < ARW_N_NODES) {
        // exclusive rowptr; deg <= ~59 (Poisson(32) over 100K rows) so 10-bit pack
        // is safe (same assumption the previous passing version relied on).
        unsigned rb = (unsigned)(s[ARW_CB2 + j] + pre + sv - v);
        s[ARW_PD + idx]  = (int)((rb << 10) | (unsigned)v);
        s[ARW_CNT + idx] = (int)rb;                 // scatter cursor starts at rowptr
    }
}

// ---------- 4. unordered scatter: one 8B (e,col) store per edge ----------
__global__ __launch_bounds__(256) void arw16896_scat(const int* __restrict__ row,
                                                     const int* __restrict__ col,
                                                     int* __restrict__ s) {
    int e = blockIdx.x * 256 + threadIdx.x;      // grid covers exactly N_EDGES
    int r = row[e], c = col[e];
    int pos = atomicAdd(&s[ARW_CNT + r], 1);     // unique slot in [rowptr, rowptr+deg)
    ((int2*)(s + ARW_EC))[pos] = make_int2(e, c);
}

// ---------- 5. per-row stable ordering: one wave per row, rank by e ----------
// rank_i = #{j in row : e_j < e_i}; e distinct -> bijection onto [0,deg).
// d <= 64 (always, in practice): fully-unrolled 64-lane shuffle compare.
// d  > 64 (paranoia fallback): O(d^2) wave-uniform global loop.
__global__ __launch_bounds__(256) void arw16896_rsort(int* __restrict__ s) {
    int tid = threadIdx.x, lane = tid & 63;
    int r = blockIdx.x * 4 + (tid >> 6);
    if (r >= ARW_N_NODES) return;
    unsigned pdv = (unsigned)s[ARW_PD + r];
    int d    = (int)(pdv & 1023u);
    int base = (int)(pdv >> 10);
    if (d == 0) return;
    const int2* ec = (const int2*)(s + ARW_EC);
    if (d <= 64) {
        int2 me = ec[base + lane];               // lane>=d reads in-bounds junk (guarded)
        int ex = me.x;
        int rk = 0;
        #pragma unroll
        for (int j = 0; j < 64; j++) {
            int ej = __shfl(ex, j, 64);
            rk += (j < d && j != lane && ej < ex) ? 1 : 0;
        }
        if (lane < d) s[ARW_COLS + base + rk] = me.y;
    } else {
        for (int ii = lane; ii < d; ii += 64) {
            int2 me = ec[base + ii];
            int rk = 0;
            for (int j = 0; j < d; j++) rk += (ec[base + j].x < me.x) ? 1 : 0;
            s[ARW_COLS + base + rk] = me.y;
        }
    }
}

// ---------- 6. walks: 4 walkers/thread (shared start node), packed pd loads ----------
// Walker w starts at w % N_NODES, so walkers {v, v+100K, v+200K, v+300K} share
// start node v. One thread runs all 4: step 0 does ONE pd load; steps 1..7 are
// 4 independent chains -> 4-way MLP per lane. Grid = 100K threads, all resident.
// MSHR-bound at ~50us: ~6.1M divergent lane-loads at ~64 outstanding misses/CU.
__global__ __launch_bounds__(256) void arw16896_walk(const float* __restrict__ ru,
                                                     const int* __restrict__ s,
                                                     float* __restrict__ o) {
    __shared__ float tg[4 * 256 * ARW_LOUT];   // 28 KB: 4 segments of 256x7
    int tid = threadIdx.x;
    int v = blockIdx.x * 256 + tid;
    if (v < ARW_N_NODES) {
        float uu[4][8];
        int cur[4];
        #pragma unroll
        for (int k = 0; k < 4; k++) {
            const float4* rp4 = (const float4*)(ru + (size_t)(v + k * ARW_N_NODES) * 8);
            float4 ra = rp4[0], rb = rp4[1];
            uu[k][0] = ra.x; uu[k][1] = ra.y; uu[k][2] = ra.z; uu[k][3] = ra.w;
            uu[k][4] = rb.x; uu[k][5] = rb.y; uu[k][6] = rb.z; uu[k][7] = rb.w;
        }
        // step 0: all 4 walkers share pd[v]; col loads hit the same row segment
        unsigned pd0 = (unsigned)s[ARW_PD + v];
        int d0  = (int)(pd0 & 1023u);
        int rp0 = (int)(pd0 >> 10);
        #pragma unroll
        for (int k = 0; k < 4; k++) {
            int off = (int)(uu[k][0] * (float)d0);   // f32 mul + trunc == reference
            if (off > d0 - 1) off = d0 - 1;
            int nxt = s[ARW_COLS + rp0 + off];       // off=-1 only if d0==0: in-bounds junk
            cur[k] = (d0 > 0) ? nxt : v;
        }
        // steps 1..7: 4 independent chains; batch the 4 pd loads, then 4 col loads
        #pragma unroll
        for (int t = 1; t < ARW_WLEN; t++) {
            unsigned pdk[4];
            #pragma unroll
            for (int k = 0; k < 4; k++) pdk[k] = (unsigned)s[ARW_PD + cur[k]];
            #pragma unroll
            for (int k = 0; k < 4; k++) {
                int d = (int)(pdk[k] & 1023u);
                int off = (int)(uu[k][t] * (float)d);
                if (off > d - 1) off = d - 1;        // d==0 -> off=-1, load stays in-bounds
                int nxt = s[ARW_COLS + (int)(pdk[k] >> 10) + off];
                cur[k] = (d > 0) ? nxt : cur[k];
                tg[k * (256 * ARW_LOUT) + tid * ARW_LOUT + (t - 1)] = (float)cur[k];
            }
        }
    }
    __syncthreads();
    int blkN = ARW_N_NODES - blockIdx.x * 256;
    if (blkN > 256) blkN = 256;
    int valid = blkN * ARW_LOUT;
    #pragma unroll
    for (int k = 0; k < 4; k++) {
        int base = ARW_ROW_LEN + ARW_N_EDGES +
                   (k * ARW_N_NODES + blockIdx.x * 256) * ARW_LOUT;
        for (int j = tid; j < valid; j += 256)
            o[base + j] = tg[k * (256 * ARW_LOUT) + j];
    }
}

// ---------- 7. merged assembly: originals + roots + ones (vectorized) ----------
__global__ __launch_bounds__(256) void arw16896_asm(const int* __restrict__ ei,
                                                    const float* __restrict__ wgt,
                                                    float* __restrict__ o) {
    int i4 = blockIdx.x * blockDim.x + threadIdx.x;
    if (i4 < ARW_N_EDGES / 4) {
        int4 r0 = ((const int4*)ei)[i4];
        int4 r1 = ((const int4*)(ei + ARW_N_EDGES))[i4];
        float4 wv = ((const float4*)wgt)[i4];
        ((float4*)o)[i4] = make_float4((float)r0.x, (float)r0.y, (float)r0.z, (float)r0.w);
        ((float4*)(o + ARW_ROW_LEN))[i4] =
            make_float4((float)r1.x, (float)r1.y, (float)r1.z, (float)r1.w);
        ((float4*)(o + 2 * ARW_ROW_LEN))[i4] = wv;
    }
    if (i4 < (ARW_N_WALKERS * ARW_LOUT) / 4) {
        int i = i4 * 4;
        float4 r;
        r.x = (float)(((i    ) / ARW_LOUT) % ARW_N_NODES);
        r.y = (float)(((i + 1) / ARW_LOUT) % ARW_N_NODES);
        r.z = (float)(((i + 2) / ARW_LOUT) % ARW_N_NODES);
        r.w = (float)(((i + 3) / ARW_LOUT) % ARW_N_NODES);
        ((float4*)(o + ARW_N_EDGES))[i4] = r;
        ((float4*)(o + 2 * ARW_ROW_LEN + ARW_N_EDGES))[i4] = make_float4(1.f, 1.f, 1.f, 1.f);
    }
}

extern "C" void kernel_launch(void* const* d_in, const int* in_sizes, int n_in,
                              void* d_out, int out_size, void* d_ws, size_t ws_size,
                              hipStream_t stream) {
    const int*   ei  = (const int*)d_in[0];
    const float* wgt = (const float*)d_in[1];
    const float* ru  = (const float*)d_in[2];
    int*   s = (int*)d_out;
    float* o = (float*)d_out;
    const int* row = ei;
    const int* col = ei + ARW_N_EDGES;

    arw16896_zero <<<ARW_NC2, 1024, 0, stream>>>(s);
    arw16896_deg  <<<ARW_N_EDGES / 256, 256, 0, stream>>>(row, s);
    arw16896_tot  <<<ARW_NC2, 1024, 0, stream>>>(s);
    arw16896_base <<<1, 128, 0, stream>>>(s);
    arw16896_ptr  <<<ARW_NC2, 1024, 0, stream>>>(s);
    arw16896_scat <<<ARW_N_EDGES / 256, 256, 0, stream>>>(row, col, s);
    arw16896_rsort<<<(ARW_N_NODES + 3) / 4, 256, 0, stream>>>(s);
    arw16896_walk <<<(ARW_N_NODES + 255) / 256, 256, 0, stream>>>(ru, s, o);
    arw16896_asm  <<<(ARW_N_EDGES / 4 + 255) / 256, 256, 0, stream>>>(ei, wgt, o);
}

// Round 3
// 335.243 us; speedup vs baseline: 1.8825x; 1.8825x over previous
//
#include <hip/hip_runtime.h>

// Problem constants
#define ARW_N_NODES   100000
#define ARW_N_EDGES   3200000
#define ARW_N_WALKERS 400000
#define ARW_WLEN      8
#define ARW_LOUT      7
#define ARW_ROW_LEN   6000000           // N_EDGES + N_WALKERS*LOUT
#define ARW_OUT_ELEMS 18000000          // float32 output elements

// Sort geometry: 196 buckets of 512 rows (b = r>>9); 3125 tiles of 1024 edges.
#define ARW_NB    196
#define ARW_NT    3125
#define ARW_TP    3136                 // padded row stride for Ht/Bt (t-contiguous)
#define ARW_TILE  1024

// Scratch inside d_out (18M floats = 72MB), int32 view; staged lifetimes:
//   Ht  @ [0, 614656)          histograms Ht[b][t] = HT + b*TP + t
//   Bt  @ [700000, 1314656)    scan bases Bt[b][t]; Bt[b][0] = bucket start
//   tot @ [1350000, +196)      per-bucket totals
//   cb  @ [1360000, +196)      bucket exclusive bases
//   pd  @ [1400000, 1500000)   packed (rowptr<<10 | deg), written by pass2
//   S2  @ [2600000, 5800000)   per-bucket unordered (q<<17|col) slots (pass2 B->C)
//   P   @ [6000000, 9200000)   packed partition (row1-orig region, dead after pass2)
//   col_s @ [12000000, 15200000) (weights region; asm overwrites last)
// walk writes float targets @ [9200000, 12000000). asm (last) overwrites all scratch.
#define ARW_HT    0
#define ARW_BT    700000
#define ARW_TOT   1350000
#define ARW_CB    1360000
#define ARW_PD    1400000
#define ARW_S2    2600000
#define ARW_P     6000000
#define ARW_COLS  12000000

__global__ void AddRandomWalkEdge_16896401342869_kernel() {}

// ---------- 1. tile histogram over 196 buckets (LDS atomics, transposed out) ----------
__global__ __launch_bounds__(1024) void arw16896_thist(const int* __restrict__ row,
                                                       int* __restrict__ s) {
    __shared__ int h[256];
    int tid = threadIdx.x;
    if (tid < 256) h[tid] = 0;
    __syncthreads();
    atomicAdd(&h[row[blockIdx.x * ARW_TILE + tid] >> 9], 1);
    __syncthreads();
    if (tid < ARW_NB) s[ARW_HT + tid * ARW_TP + blockIdx.x] = h[tid];
}

// ---------- 2a. per-bucket totals (196 blocks, 1024 thr, shuffle reduce) ----------
__global__ __launch_bounds__(1024) void arw16896_btot(int* __restrict__ s) {
    __shared__ int wsum[16];
    int b = blockIdx.x, tid = threadIdx.x, lane = tid & 63, wid = tid >> 6;
    int acc = 0;
    for (int t = tid; t < ARW_NT; t += 1024) acc += s[ARW_HT + b * ARW_TP + t];
    #pragma unroll
    for (int off = 32; off > 0; off >>= 1) acc += __shfl_down(acc, off, 64);
    if (lane == 0) wsum[wid] = acc;
    __syncthreads();
    if (tid == 0) {
        int a = 0;
        #pragma unroll
        for (int w = 0; w < 16; w++) a += wsum[w];
        s[ARW_TOT + b] = a;
    }
}

// ---------- 2b. exclusive scan of 196 bucket totals (1 block) ----------
__global__ __launch_bounds__(256) void arw16896_bbase(int* __restrict__ s) {
    __shared__ int sm[256];
    int tid = threadIdx.x;
    int v = (tid < ARW_NB) ? s[ARW_TOT + tid] : 0;
    sm[tid] = v;
    __syncthreads();
    for (int off = 1; off < 256; off <<= 1) {
        int x = 0;
        if (tid >= off) x = sm[tid - off];
        __syncthreads();
        sm[tid] += x;
        __syncthreads();
    }
    if (tid < ARW_NB) s[ARW_CB + tid] = sm[tid] - v;
}

// ---------- 2c. per-bucket chunked exclusive scan -> Bt[b][t] (shuffle) ----------
__global__ __launch_bounds__(1024) void arw16896_bscan2(int* __restrict__ s) {
    __shared__ int wsum[16];
    int b = blockIdx.x, tid = threadIdx.x, lane = tid & 63, wid = tid >> 6;
    int carry = s[ARW_CB + b];
    for (int c0 = 0; c0 < ARW_NT; c0 += 1024) {
        int t = c0 + tid;
        int v = (t < ARW_NT) ? s[ARW_HT + b * ARW_TP + t] : 0;
        int sv = v;
        #pragma unroll
        for (int off = 1; off < 64; off <<= 1) {
            int x = __shfl_up(sv, off, 64);
            if (lane >= off) sv += x;
        }
        if (lane == 63) wsum[wid] = sv;
        __syncthreads();
        int pre = 0, tot = 0;
        #pragma unroll
        for (int w = 0; w < 16; w++) {
            int x = wsum[w];
            if (w < wid) pre += x;
            tot += x;
        }
        if (t < ARW_NT) s[ARW_BT + b * ARW_TP + t] = carry + pre + sv - v;
        carry += tot;
        __syncthreads();
    }
}

// ---------- 3. stable partition into buckets (ballot multisplit, no atomics) ----------
__global__ __launch_bounds__(1024) void arw16896_part(const int* __restrict__ row,
                                                      const int* __restrict__ col,
                                                      int* __restrict__ s) {
    __shared__ unsigned W[16 * 256];
    int tid  = threadIdx.x;
    int wave = tid >> 6, lane = tid & 63;
    int e = blockIdx.x * ARW_TILE + tid;
    int r = row[e], cv = col[e];
    int b = r >> 9;
    W[tid] = 0; W[tid + 1024] = 0; W[tid + 2048] = 0; W[tid + 3072] = 0;
    __syncthreads();
    unsigned long long mask = ~0ULL;
    #pragma unroll
    for (int bit = 0; bit < 8; bit++) {
        unsigned long long bal = __ballot((b >> bit) & 1);
        mask &= ((b >> bit) & 1) ? bal : ~bal;
    }
    int rankw = __popcll(mask & ((1ULL << lane) - 1ULL));
    W[wave * 256 + b] = (unsigned)__popcll(mask);
    __syncthreads();
    int cross = 0;
    for (int w2 = 0; w2 < 16; w2++) {
        if (w2 >= wave) break;
        cross += (int)W[w2 * 256 + b];
    }
    int base = s[ARW_BT + b * ARW_TP + blockIdx.x];
    s[ARW_P + base + cross + rankw] = ((r & 511) << 17) | cv;   // pack(local_r, col)
}

// ---------- 4. per-bucket CSR finish: hist+scan, L2-confined unordered scatter,
//                per-row rank-by-q (one wave per row). ----------
// P within a bucket is in original-e order (part is stable). Phase B scatters each
// edge to a unique slot of its row segment (LDS cursor; order arbitrary), packing
// q = within-bucket index (15b, bucket <= ~17K) with col (17b). Phase C restores
// stability: rank by q within the row (q unique) via 64-lane shuffle compare.
// All B/C traffic confined to this bucket's ~65KB windows -> L2, no HBM scatter.
__global__ __launch_bounds__(1024) void arw16896_pass2(int* __restrict__ s) {
    __shared__ int hist[512], pref[512], cnt[512];
    int tid = threadIdx.x;
    int b = blockIdx.x;
    int start = s[ARW_BT + b * ARW_TP];
    int end   = (b == ARW_NB - 1) ? ARW_N_EDGES : s[ARW_BT + (b + 1) * ARW_TP];
    int ce = end - start;
    int rows0 = b << 9;
    int nrows = ARW_N_NODES - rows0; if (nrows > 512) nrows = 512;

    // Phase A: 512-bin histogram + inclusive scan; emit pd
    if (tid < 512) { hist[tid] = 0; cnt[tid] = 0; }
    __syncthreads();
    for (int k = tid; k < ce; k += 1024)
        atomicAdd(&hist[(unsigned)s[ARW_P + start + k] >> 17], 1);
    __syncthreads();
    if (tid < 512) pref[tid] = hist[tid];
    __syncthreads();
    for (int off = 1; off < 512; off <<= 1) {
        int x = 0;
        if (tid < 512 && tid >= off) x = pref[tid - off];
        __syncthreads();
        if (tid < 512) pref[tid] += x;
        __syncthreads();
    }
    if (tid < nrows) {
        // packed (rowptr<<10 | deg); deg Poisson(32) << 1023. unsigned: rp<<10 > 2^31.
        unsigned deg = (unsigned)hist[tid];
        unsigned rp  = (unsigned)(start + pref[tid] - hist[tid]);
        s[ARW_PD + rows0 + tid] = (int)((rp << 10) | deg);
    }
    __syncthreads();

    // Phase B: unordered scatter into S2 bucket window (no barriers in loop)
    for (int k = tid; k < ce; k += 1024) {
        unsigned p = (unsigned)s[ARW_P + start + k];
        unsigned lr = p >> 17;
        int pos = atomicAdd(&cnt[lr], 1);
        s[ARW_S2 + start + (pref[lr] - hist[lr]) + pos] =
            (int)(((unsigned)k << 17) | (p & 0x1FFFFu));
    }
    __syncthreads();

    // Phase C: per-row stable order via rank-by-q
    int wave = tid >> 6, lane = tid & 63;
    for (int rr = wave; rr < nrows; rr += 16) {
        int d = hist[rr];
        if (d == 0) continue;
        int gbase = start + pref[rr] - hist[rr];
        if (d <= 64) {
            unsigned val = (unsigned)s[ARW_S2 + gbase + (lane < d ? lane : 0)];
            int q = (int)(val >> 17);
            int rk = 0;
            #pragma unroll
            for (int j = 0; j < 64; j++) {
                int qj = __shfl(q, j, 64);
                rk += (j < d && qj < q) ? 1 : 0;
            }
            if (lane < d) s[ARW_COLS + gbase + rk] = (int)(val & 0x1FFFFu);
        } else {                                   // paranoia fallback, d>64
            for (int ii = lane; ii < d; ii += 64) {
                unsigned vi = (unsigned)s[ARW_S2 + gbase + ii];
                int qi = (int)(vi >> 17), rk = 0;
                for (int j = 0; j < d; j++) {
                    unsigned vj = (unsigned)s[ARW_S2 + gbase + j];
                    rk += ((int)(vj >> 17) < qi) ? 1 : 0;
                }
                s[ARW_COLS + gbase + rk] = (int)(vi & 0x1FFFFu);
            }
        }
    }
}

// ---------- 5. walks: 4 walkers/thread (shared start node), packed pd loads ----------
// Walker w starts at w % N_NODES, so walkers {v, v+100K, v+200K, v+300K} share
// start node v. One thread runs all 4: step 0 does ONE pd load; steps 1..7 are
// 4 independent chains -> 4-way MLP per lane. Grid = 100K threads, all resident.
// MSHR-bound at ~50us: ~6.1M divergent lane-loads at ~64 outstanding misses/CU.
__global__ __launch_bounds__(256) void arw16896_walk(const float* __restrict__ ru,
                                                     const int* __restrict__ s,
                                                     float* __restrict__ o) {
    __shared__ float tg[4 * 256 * ARW_LOUT];   // 28 KB: 4 segments of 256x7
    int tid = threadIdx.x;
    int v = blockIdx.x * 256 + tid;
    if (v < ARW_N_NODES) {
        float uu[4][8];
        int cur[4];
        #pragma unroll
        for (int k = 0; k < 4; k++) {
            const float4* rp4 = (const float4*)(ru + (size_t)(v + k * ARW_N_NODES) * 8);
            float4 ra = rp4[0], rb = rp4[1];
            uu[k][0] = ra.x; uu[k][1] = ra.y; uu[k][2] = ra.z; uu[k][3] = ra.w;
            uu[k][4] = rb.x; uu[k][5] = rb.y; uu[k][6] = rb.z; uu[k][7] = rb.w;
        }
        // step 0: all 4 walkers share pd[v]; col loads hit the same row segment
        unsigned pd0 = (unsigned)s[ARW_PD + v];
        int d0  = (int)(pd0 & 1023u);
        int rp0 = (int)(pd0 >> 10);
        #pragma unroll
        for (int k = 0; k < 4; k++) {
            int off = (int)(uu[k][0] * (float)d0);   // f32 mul + trunc == reference
            if (off > d0 - 1) off = d0 - 1;
            int nxt = s[ARW_COLS + rp0 + off];       // off=-1 only if d0==0: in-bounds junk
            cur[k] = (d0 > 0) ? nxt : v;
        }
        // steps 1..7: 4 independent chains; batch the 4 pd loads, then 4 col loads
        #pragma unroll
        for (int t = 1; t < ARW_WLEN; t++) {
            unsigned pdk[4];
            #pragma unroll
            for (int k = 0; k < 4; k++) pdk[k] = (unsigned)s[ARW_PD + cur[k]];
            #pragma unroll
            for (int k = 0; k < 4; k++) {
                int d = (int)(pdk[k] & 1023u);
                int off = (int)(uu[k][t] * (float)d);
                if (off > d - 1) off = d - 1;        // d==0 -> off=-1, load stays in-bounds
                int nxt = s[ARW_COLS + (int)(pdk[k] >> 10) + off];
                cur[k] = (d > 0) ? nxt : cur[k];
                tg[k * (256 * ARW_LOUT) + tid * ARW_LOUT + (t - 1)] = (float)cur[k];
            }
        }
    }
    __syncthreads();
    int blkN = ARW_N_NODES - blockIdx.x * 256;
    if (blkN > 256) blkN = 256;
    int valid = blkN * ARW_LOUT;
    #pragma unroll
    for (int k = 0; k < 4; k++) {
        int base = ARW_ROW_LEN + ARW_N_EDGES +
                   (k * ARW_N_NODES + blockIdx.x * 256) * ARW_LOUT;
        for (int j = tid; j < valid; j += 256)
            o[base + j] = tg[k * (256 * ARW_LOUT) + j];
    }
}

// ---------- 6. merged assembly: originals + roots + ones (vectorized) ----------
__global__ __launch_bounds__(256) void arw16896_asm(const int* __restrict__ ei,
                                                    const float* __restrict__ wgt,
                                                    float* __restrict__ o) {
    int i4 = blockIdx.x * blockDim.x + threadIdx.x;
    if (i4 < ARW_N_EDGES / 4) {
        int4 r0 = ((const int4*)ei)[i4];
        int4 r1 = ((const int4*)(ei + ARW_N_EDGES))[i4];
        float4 wv = ((const float4*)wgt)[i4];
        ((float4*)o)[i4] = make_float4((float)r0.x, (float)r0.y, (float)r0.z, (float)r0.w);
        ((float4*)(o + ARW_ROW_LEN))[i4] =
            make_float4((float)r1.x, (float)r1.y, (float)r1.z, (float)r1.w);
        ((float4*)(o + 2 * ARW_ROW_LEN))[i4] = wv;
    }
    if (i4 < (ARW_N_WALKERS * ARW_LOUT) / 4) {
        int i = i4 * 4;
        float4 r;
        r.x = (float)(((i    ) / ARW_LOUT) % ARW_N_NODES);
        r.y = (float)(((i + 1) / ARW_LOUT) % ARW_N_NODES);
        r.z = (float)(((i + 2) / ARW_LOUT) % ARW_N_NODES);
        r.w = (float)(((i + 3) / ARW_LOUT) % ARW_N_NODES);
        ((float4*)(o + ARW_N_EDGES))[i4] = r;
        ((float4*)(o + 2 * ARW_ROW_LEN + ARW_N_EDGES))[i4] = make_float4(1.f, 1.f, 1.f, 1.f);
    }
}

extern "C" void kernel_launch(void* const* d_in, const int* in_sizes, int n_in,
                              void* d_out, int out_size, void* d_ws, size_t ws_size,
                              hipStream_t stream) {
    const int*   ei  = (const int*)d_in[0];
    const float* wgt = (const float*)d_in[1];
    const float* ru  = (const float*)d_in[2];
    int*   s = (int*)d_out;
    float* o = (float*)d_out;
    const int* row = ei;
    const int* col = ei + ARW_N_EDGES;

    arw16896_thist <<<ARW_NT, 1024, 0, stream>>>(row, s);
    arw16896_btot  <<<ARW_NB, 1024, 0, stream>>>(s);
    arw16896_bbase <<<1, 256, 0, stream>>>(s);
    arw16896_bscan2<<<ARW_NB, 1024, 0, stream>>>(s);
    arw16896_part  <<<ARW_NT, 1024, 0, stream>>>(row, col, s);
    arw16896_pass2 <<<ARW_NB, 1024, 0, stream>>>(s);
    arw16896_walk  <<<(ARW_N_NODES + 255) / 256, 256, 0, stream>>>(ru, s, o);
    arw16896_asm   <<<(ARW_N_EDGES / 4 + 255) / 256, 256, 0, stream>>>(ei, wgt, o);
}

// Round 4
// 265.159 us; speedup vs baseline: 2.3801x; 1.2643x over previous
//
#include <hip/hip_runtime.h>

// Problem constants
#define ARW_N_NODES   100000
#define ARW_N_EDGES   3200000
#define ARW_N_WALKERS 400000
#define ARW_WLEN      8
#define ARW_LOUT      7
#define ARW_ROW_LEN   6000000           // N_EDGES + N_WALKERS*LOUT
#define ARW_OUT_ELEMS 18000000          // float32 output elements

// Sort geometry: 196 buckets of 512 rows (b = r>>9); 3125 tiles of 1024 edges.
#define ARW_NB    196
#define ARW_NT    3125
#define ARW_TP    3136                 // padded row stride for Ht/Bt (t-contiguous)
#define ARW_TILE  1024

// Scratch inside d_out (18M floats = 72MB), int32 view; staged lifetimes:
//   Ht  @ [0, 614656)          histograms Ht[b][t] = HT + b*TP + t
//   Bt  @ [700000, 1314656)    scan bases Bt[b][t]; Bt[b][0] = bucket start
//   tot @ [1350000, +196)      per-bucket totals
//   cb  @ [1360000, +196)      bucket exclusive bases
//   pd  @ [1400000, 1500000)   packed (rowptr<<10 | deg), written by pass2
//   ecp @ [2600000, 9000000)   int2 (col, pd[col]) fused walk table (after pass2;
//                              overwrites P's tail — P dead by then)
//   P   @ [6000000, 9200000)   packed partition (row1-orig region, dead after pass2)
//   col_s @ [12000000, 15200000) (weights region; asm overwrites last)
// walk writes float targets @ [9200000, 12000000). asm (last) overwrites all scratch.
#define ARW_HT    0
#define ARW_BT    700000
#define ARW_TOT   1350000
#define ARW_CB    1360000
#define ARW_PD    1400000
#define ARW_ECP   2600000
#define ARW_P     6000000
#define ARW_COLS  12000000

__global__ void AddRandomWalkEdge_16896401342869_kernel() {}

// ---------- 1. tile histogram over 196 buckets (LDS atomics, transposed out) ----------
__global__ __launch_bounds__(1024) void arw16896_thist(const int* __restrict__ row,
                                                       int* __restrict__ s) {
    __shared__ int h[256];
    int tid = threadIdx.x;
    if (tid < 256) h[tid] = 0;
    __syncthreads();
    atomicAdd(&h[row[blockIdx.x * ARW_TILE + tid] >> 9], 1);
    __syncthreads();
    if (tid < ARW_NB) s[ARW_HT + tid * ARW_TP + blockIdx.x] = h[tid];
}

// ---------- 2a. per-bucket totals (196 blocks, 1024 thr, shuffle reduce) ----------
__global__ __launch_bounds__(1024) void arw16896_btot(int* __restrict__ s) {
    __shared__ int wsum[16];
    int b = blockIdx.x, tid = threadIdx.x, lane = tid & 63, wid = tid >> 6;
    int acc = 0;
    for (int t = tid; t < ARW_NT; t += 1024) acc += s[ARW_HT + b * ARW_TP + t];
    #pragma unroll
    for (int off = 32; off > 0; off >>= 1) acc += __shfl_down(acc, off, 64);
    if (lane == 0) wsum[wid] = acc;
    __syncthreads();
    if (tid == 0) {
        int a = 0;
        #pragma unroll
        for (int w = 0; w < 16; w++) a += wsum[w];
        s[ARW_TOT + b] = a;
    }
}

// ---------- 2b. exclusive scan of 196 bucket totals (1 block) ----------
__global__ __launch_bounds__(256) void arw16896_bbase(int* __restrict__ s) {
    __shared__ int sm[256];
    int tid = threadIdx.x;
    int v = (tid < ARW_NB) ? s[ARW_TOT + tid] : 0;
    sm[tid] = v;
    __syncthreads();
    for (int off = 1; off < 256; off <<= 1) {
        int x = 0;
        if (tid >= off) x = sm[tid - off];
        __syncthreads();
        sm[tid] += x;
        __syncthreads();
    }
    if (tid < ARW_NB) s[ARW_CB + tid] = sm[tid] - v;
}

// ---------- 2c. per-bucket chunked exclusive scan -> Bt[b][t] (shuffle) ----------
__global__ __launch_bounds__(1024) void arw16896_bscan2(int* __restrict__ s) {
    __shared__ int wsum[16];
    int b = blockIdx.x, tid = threadIdx.x, lane = tid & 63, wid = tid >> 6;
    int carry = s[ARW_CB + b];
    for (int c0 = 0; c0 < ARW_NT; c0 += 1024) {
        int t = c0 + tid;
        int v = (t < ARW_NT) ? s[ARW_HT + b * ARW_TP + t] : 0;
        int sv = v;
        #pragma unroll
        for (int off = 1; off < 64; off <<= 1) {
            int x = __shfl_up(sv, off, 64);
            if (lane >= off) sv += x;
        }
        if (lane == 63) wsum[wid] = sv;
        __syncthreads();
        int pre = 0, tot = 0;
        #pragma unroll
        for (int w = 0; w < 16; w++) {
            int x = wsum[w];
            if (w < wid) pre += x;
            tot += x;
        }
        if (t < ARW_NT) s[ARW_BT + b * ARW_TP + t] = carry + pre + sv - v;
        carry += tot;
        __syncthreads();
    }
}

// ---------- 3. stable partition into buckets (ballot multisplit, no atomics) ----------
__global__ __launch_bounds__(1024) void arw16896_part(const int* __restrict__ row,
                                                      const int* __restrict__ col,
                                                      int* __restrict__ s) {
    __shared__ unsigned W[16 * 256];
    int tid  = threadIdx.x;
    int wave = tid >> 6, lane = tid & 63;
    int e = blockIdx.x * ARW_TILE + tid;
    int r = row[e], cv = col[e];
    int b = r >> 9;
    W[tid] = 0; W[tid + 1024] = 0; W[tid + 2048] = 0; W[tid + 3072] = 0;
    __syncthreads();
    unsigned long long mask = ~0ULL;
    #pragma unroll
    for (int bit = 0; bit < 8; bit++) {
        unsigned long long bal = __ballot((b >> bit) & 1);
        mask &= ((b >> bit) & 1) ? bal : ~bal;
    }
    int rankw = __popcll(mask & ((1ULL << lane) - 1ULL));
    W[wave * 256 + b] = (unsigned)__popcll(mask);
    __syncthreads();
    int cross = 0;
    for (int w2 = 0; w2 < 16; w2++) {
        if (w2 >= wave) break;
        cross += (int)W[w2 * 256 + b];
    }
    int base = s[ARW_BT + b * ARW_TP + blockIdx.x];
    s[ARW_P + base + cross + rankw] = ((r & 511) << 17) | cv;   // pack(local_r, col)
}

// ---------- 4. per-bucket stable scatter -> col_s + packed pd ----------
// (R1's proven ballot multisplit, ~46us.)
// Pass A: 512-bin histogram + scan (also emits pd = rowptr<<10 | deg).
// Pass B: chunked 9-bit ballot multisplit: in-wave rank + cross-wave LDS table
//         + running per-row count -> stable global position. No sorting.
__global__ __launch_bounds__(1024) void arw16896_pass2(int* __restrict__ s) {
    __shared__ unsigned W[16 * 512];          // 32 KB
    __shared__ int hist[512], pref[512], runc[512];
    int tid = threadIdx.x, lane = tid & 63, wave = tid >> 6;
    int b = blockIdx.x;
    int start = s[ARW_BT + b * ARW_TP];
    int end   = (b == ARW_NB - 1) ? ARW_N_EDGES : s[ARW_BT + (b + 1) * ARW_TP];
    int cnt = end - start;
    int rows0 = b << 9;
    int nrows = ARW_N_NODES - rows0; if (nrows > 512) nrows = 512;

    // Pass A: histogram
    if (tid < 512) hist[tid] = 0;
    __syncthreads();
    for (int k = tid; k < cnt; k += 1024)
        atomicAdd(&hist[(unsigned)s[ARW_P + start + k] >> 17], 1);
    __syncthreads();
    if (tid < 512) pref[tid] = hist[tid];
    __syncthreads();
    for (int off = 1; off < 512; off <<= 1) {     // inclusive scan of hist
        int x = 0;
        if (tid < 512 && tid >= off) x = pref[tid - off];
        __syncthreads();
        if (tid < 512) pref[tid] += x;
        __syncthreads();
    }
    if (tid < 512) runc[tid] = 0;
    if (tid < nrows) {
        // packed (rowptr<<10 | deg). rowptr < 3.2M (22 bits); deg is Poisson(32)
        // on this input, always << 1023 (10 bits). unsigned: rp<<10 can exceed 2^31.
        unsigned deg = (unsigned)hist[tid];
        unsigned rp  = (unsigned)(start + pref[tid] - hist[tid]);
        s[ARW_PD + rows0 + tid] = (int)((rp << 10) | deg);
    }
    __syncthreads();

    // Pass B: stable scatter
    for (int c0 = 0; c0 < cnt; c0 += 1024) {
        int k = c0 + tid;
        int valid = (k < cnt) ? 1 : 0;
        unsigned p = valid ? (unsigned)s[ARW_P + start + k] : 0u;
        unsigned lr = p >> 17;                     // 9 bits
        #pragma unroll
        for (int j = 0; j < 8; j++) W[tid + j * 1024] = 0;
        __syncthreads();
        unsigned long long mask = ~0ULL;
        #pragma unroll
        for (int bit = 0; bit < 9; bit++) {
            unsigned long long bal = __ballot((lr >> bit) & 1u);
            mask &= ((lr >> bit) & 1u) ? bal : ~bal;
        }
        mask &= __ballot(valid);
        int rankw = __popcll(mask & ((1ULL << lane) - 1ULL));
        if (valid) W[wave * 512 + lr] = (unsigned)__popcll(mask);
        __syncthreads();
        if (valid) {
            int cross = 0;
            for (int w2 = 0; w2 < 16; w2++) {
                if (w2 >= wave) break;
                cross += (int)W[w2 * 512 + lr];
            }
            int pos = start + (pref[lr] - hist[lr]) + runc[lr] + cross + rankw;
            s[ARW_COLS + pos] = (int)(p & 0x1FFFFu);
        }
        __syncthreads();
        if (tid < 512) {
            int a = 0;
            #pragma unroll
            for (int w = 0; w < 16; w++) a += (int)W[w * 512 + tid];
            runc[tid] += a;
        }
        __syncthreads();
    }
}

// ---------- 5. fused walk table: ecp[i] = (col_s[i], pd[col_s[i]]) ----------
// Coalesced col_s read; pd gather hits a 400KB L2-resident table; 8B coalesced
// writes. Lets each walk step do ONE random 8B load instead of two 4B loads.
__global__ __launch_bounds__(256) void arw16896_ecp(int* __restrict__ s) {
    int i = blockIdx.x * 256 + threadIdx.x;      // grid covers exactly N_EDGES
    int c = s[ARW_COLS + i];
    ((int2*)(s + ARW_ECP))[i] = make_int2(c, s[ARW_PD + c]);
}

// ---------- 6. walks: 4 walkers/thread, ONE fused 8B load per step ----------
// Walker w starts at w % N_NODES, so walkers {v, v+100K, v+200K, v+300K} share
// start node v; one thread runs all 4 as independent chains (4-way MLP).
// Each step: off from current pd; ecp[rowptr+off] yields next node AND its pd.
// Chain depth per step: 1 load (was 2). Random lane-loads: ~2.9M (was 6.1M).
__global__ __launch_bounds__(256) void arw16896_walk(const float* __restrict__ ru,
                                                     const int* __restrict__ s,
                                                     float* __restrict__ o) {
    __shared__ float tg[4 * 256 * ARW_LOUT];   // 28 KB: 4 segments of 256x7
    int tid = threadIdx.x;
    int v = blockIdx.x * 256 + tid;
    if (v < ARW_N_NODES) {
        const int2* ecp = (const int2*)(s + ARW_ECP);
        float uu[4][8];
        int cur[4]; unsigned pdc[4];
        #pragma unroll
        for (int k = 0; k < 4; k++) {
            const float4* rp4 = (const float4*)(ru + (size_t)(v + k * ARW_N_NODES) * 8);
            float4 ra = rp4[0], rb = rp4[1];
            uu[k][0] = ra.x; uu[k][1] = ra.y; uu[k][2] = ra.z; uu[k][3] = ra.w;
            uu[k][4] = rb.x; uu[k][5] = rb.y; uu[k][6] = rb.z; uu[k][7] = rb.w;
        }
        // step 0: all 4 walkers share pd[v]; 4 ecp loads land in the same row segment
        unsigned pd0 = (unsigned)s[ARW_PD + v];
        int d0  = (int)(pd0 & 1023u);
        int rp0 = (int)(pd0 >> 10);
        #pragma unroll
        for (int k = 0; k < 4; k++) {
            int off = (int)(uu[k][0] * (float)d0);   // f32 mul + trunc == reference
            if (off > d0 - 1) off = d0 - 1;
            int2 e0 = ecp[rp0 + off];                // off=-1 only if d0==0: in-bounds junk
            cur[k] = (d0 > 0) ? e0.x : v;
            pdc[k] = (d0 > 0) ? (unsigned)e0.y : pd0;
        }
        // steps 1..7: 4 independent chains, one fused load each
        #pragma unroll
        for (int t = 1; t < ARW_WLEN; t++) {
            #pragma unroll
            for (int k = 0; k < 4; k++) {
                int d = (int)(pdc[k] & 1023u);
                int off = (int)(uu[k][t] * (float)d);
                if (off > d - 1) off = d - 1;        // d==0 -> off=-1, load stays in-bounds
                int2 en = ecp[(int)(pdc[k] >> 10) + off];
                if (d > 0) { cur[k] = en.x; pdc[k] = (unsigned)en.y; }
                tg[k * (256 * ARW_LOUT) + tid * ARW_LOUT + (t - 1)] = (float)cur[k];
            }
        }
    }
    __syncthreads();
    int blkN = ARW_N_NODES - blockIdx.x * 256;
    if (blkN > 256) blkN = 256;
    int valid = blkN * ARW_LOUT;
    #pragma unroll
    for (int k = 0; k < 4; k++) {
        int base = ARW_ROW_LEN + ARW_N_EDGES +
                   (k * ARW_N_NODES + blockIdx.x * 256) * ARW_LOUT;
        for (int j = tid; j < valid; j += 256)
            o[base + j] = tg[k * (256 * ARW_LOUT) + j];
    }
}

// ---------- 7. merged assembly: originals + roots + ones (vectorized) ----------
__global__ __launch_bounds__(256) void arw16896_asm(const int* __restrict__ ei,
                                                    const float* __restrict__ wgt,
                                                    float* __restrict__ o) {
    int i4 = blockIdx.x * blockDim.x + threadIdx.x;
    if (i4 < ARW_N_EDGES / 4) {
        int4 r0 = ((const int4*)ei)[i4];
        int4 r1 = ((const int4*)(ei + ARW_N_EDGES))[i4];
        float4 wv = ((const float4*)wgt)[i4];
        ((float4*)o)[i4] = make_float4((float)r0.x, (float)r0.y, (float)r0.z, (float)r0.w);
        ((float4*)(o + ARW_ROW_LEN))[i4] =
            make_float4((float)r1.x, (float)r1.y, (float)r1.z, (float)r1.w);
        ((float4*)(o + 2 * ARW_ROW_LEN))[i4] = wv;
    }
    if (i4 < (ARW_N_WALKERS * ARW_LOUT) / 4) {
        int i = i4 * 4;
        float4 r;
        r.x = (float)(((i    ) / ARW_LOUT) % ARW_N_NODES);
        r.y = (float)(((i + 1) / ARW_LOUT) % ARW_N_NODES);
        r.z = (float)(((i + 2) / ARW_LOUT) % ARW_N_NODES);
        r.w = (float)(((i + 3) / ARW_LOUT) % ARW_N_NODES);
        ((float4*)(o + ARW_N_EDGES))[i4] = r;
        ((float4*)(o + 2 * ARW_ROW_LEN + ARW_N_EDGES))[i4] = make_float4(1.f, 1.f, 1.f, 1.f);
    }
}

extern "C" void kernel_launch(void* const* d_in, const int* in_sizes, int n_in,
                              void* d_out, int out_size, void* d_ws, size_t ws_size,
                              hipStream_t stream) {
    const int*   ei  = (const int*)d_in[0];
    const float* wgt = (const float*)d_in[1];
    const float* ru  = (const float*)d_in[2];
    int*   s = (int*)d_out;
    float* o = (float*)d_out;
    const int* row = ei;
    const int* col = ei + ARW_N_EDGES;

    arw16896_thist <<<ARW_NT, 1024, 0, stream>>>(row, s);
    arw16896_btot  <<<ARW_NB, 1024, 0, stream>>>(s);
    arw16896_bbase <<<1, 256, 0, stream>>>(s);
    arw16896_bscan2<<<ARW_NB, 1024, 0, stream>>>(s);
    arw16896_part  <<<ARW_NT, 1024, 0, stream>>>(row, col, s);
    arw16896_pass2 <<<ARW_NB, 1024, 0, stream>>>(s);
    arw16896_ecp   <<<ARW_N_EDGES / 256, 256, 0, stream>>>(s);
    arw16896_walk  <<<(ARW_N_NODES + 255) / 256, 256, 0, stream>>>(ru, s, o);
    arw16896_asm   <<<(ARW_N_EDGES / 4 + 255) / 256, 256, 0, stream>>>(ei, wgt, o);
}

// Round 5
// 263.424 us; speedup vs baseline: 2.3957x; 1.0066x over previous
//
#include <hip/hip_runtime.h>

// Problem constants
#define ARW_N_NODES   100000
#define ARW_N_EDGES   3200000
#define ARW_N_WALKERS 400000
#define ARW_WLEN      8
#define ARW_LOUT      7
#define ARW_ROW_LEN   6000000           // N_EDGES + N_WALKERS*LOUT
#define ARW_OUT_ELEMS 18000000          // float32 output elements

// Sort geometry: 196 buckets of 512 rows (b = r>>9); 3125 tiles of 1024 edges.
#define ARW_NB    196
#define ARW_NT    3125
#define ARW_TP    3136                 // padded row stride for Ht/Bt (t-contiguous)
#define ARW_TILE  1024
#define ARW_TPB   25                   // tiles per thist block (3125 = 125*25)

// Scratch inside d_out (18M floats = 72MB), int32 view; staged lifetimes:
//   Ht  @ [0, 614656)          histograms Ht[b][t] = HT + b*TP + t
//   Bt  @ [700000, 1314656)    scan bases Bt[b][t]; Bt[b][0] = bucket start
//   tot @ [1350000, +196)      per-bucket totals
//   cb  @ [1360000, +196)      bucket exclusive bases
//   pd  @ [1400000, 1500000)   packed (rowptr<<10 | deg), written by pass2
//   c16 @ [2600000, 4200000)   u16 plane of col_s (6.4MB random-hot in walk)
//   bits@ [4300000, 4400000)   1-bit high plane of col_s (u64-indexed, 400KB)
//   P   @ [6000000, 9200000)   packed partition (row1-orig region, dead after pass2)
//   col_s @ [12000000, 15200000) full cols from pass2 (weights region; asm last)
// walk writes float targets @ [9200000, 12000000). asm (last) overwrites all scratch.
#define ARW_HT    0
#define ARW_BT    700000
#define ARW_TOT   1350000
#define ARW_CB    1360000
#define ARW_PD    1400000
#define ARW_C16   2600000
#define ARW_BITS  4300000
#define ARW_P     6000000
#define ARW_COLS  12000000

__global__ void AddRandomWalkEdge_16896401342869_kernel() {}

// ---------- 1. tile histogram, 25 tiles/block (kills write-allocate storm) ----------
// Old: each tile wrote 196 ints at stride 12.5KB -> 612K partial-line
// write-allocates (~39MB hidden traffic). Now 25 consecutive t-slots per bucket
// are written as one run -> ~49K lines (~2.5MB).
__global__ __launch_bounds__(1024) void arw16896_thist(const int* __restrict__ row,
                                                       int* __restrict__ s) {
    __shared__ int h[ARW_TPB * 256];
    int tid = threadIdx.x;
    for (int x = tid; x < ARW_TPB * 256; x += 1024) h[x] = 0;
    __syncthreads();
    int base_e = blockIdx.x * (ARW_TPB * ARW_TILE) + tid;
    #pragma unroll
    for (int j = 0; j < ARW_TPB; j++)
        atomicAdd(&h[j * 256 + (row[base_e + j * 1024] >> 9)], 1);
    __syncthreads();
    for (int x = tid; x < ARW_TPB * ARW_NB; x += 1024) {
        int b = x / ARW_TPB, j = x % ARW_TPB;
        s[ARW_HT + b * ARW_TP + blockIdx.x * ARW_TPB + j] = h[j * 256 + b];
    }
}

// ---------- 2a. per-bucket totals (196 blocks, 1024 thr, shuffle reduce) ----------
__global__ __launch_bounds__(1024) void arw16896_btot(int* __restrict__ s) {
    __shared__ int wsum[16];
    int b = blockIdx.x, tid = threadIdx.x, lane = tid & 63, wid = tid >> 6;
    int acc = 0;
    for (int t = tid; t < ARW_NT; t += 1024) acc += s[ARW_HT + b * ARW_TP + t];
    #pragma unroll
    for (int off = 32; off > 0; off >>= 1) acc += __shfl_down(acc, off, 64);
    if (lane == 0) wsum[wid] = acc;
    __syncthreads();
    if (tid == 0) {
        int a = 0;
        #pragma unroll
        for (int w = 0; w < 16; w++) a += wsum[w];
        s[ARW_TOT + b] = a;
    }
}

// ---------- 2b. exclusive scan of 196 bucket totals (1 block) ----------
__global__ __launch_bounds__(256) void arw16896_bbase(int* __restrict__ s) {
    __shared__ int sm[256];
    int tid = threadIdx.x;
    int v = (tid < ARW_NB) ? s[ARW_TOT + tid] : 0;
    sm[tid] = v;
    __syncthreads();
    for (int off = 1; off < 256; off <<= 1) {
        int x = 0;
        if (tid >= off) x = sm[tid - off];
        __syncthreads();
        sm[tid] += x;
        __syncthreads();
    }
    if (tid < ARW_NB) s[ARW_CB + tid] = sm[tid] - v;
}

// ---------- 2c. per-bucket chunked exclusive scan -> Bt[b][t] (shuffle) ----------
__global__ __launch_bounds__(1024) void arw16896_bscan2(int* __restrict__ s) {
    __shared__ int wsum[16];
    int b = blockIdx.x, tid = threadIdx.x, lane = tid & 63, wid = tid >> 6;
    int carry = s[ARW_CB + b];
    for (int c0 = 0; c0 < ARW_NT; c0 += 1024) {
        int t = c0 + tid;
        int v = (t < ARW_NT) ? s[ARW_HT + b * ARW_TP + t] : 0;
        int sv = v;
        #pragma unroll
        for (int off = 1; off < 64; off <<= 1) {
            int x = __shfl_up(sv, off, 64);
            if (lane >= off) sv += x;
        }
        if (lane == 63) wsum[wid] = sv;
        __syncthreads();
        int pre = 0, tot = 0;
        #pragma unroll
        for (int w = 0; w < 16; w++) {
            int x = wsum[w];
            if (w < wid) pre += x;
            tot += x;
        }
        if (t < ARW_NT) s[ARW_BT + b * ARW_TP + t] = carry + pre + sv - v;
        carry += tot;
        __syncthreads();
    }
}

// ---------- 3. stable partition into buckets (ballot multisplit, no atomics) ----------
__global__ __launch_bounds__(1024) void arw16896_part(const int* __restrict__ row,
                                                      const int* __restrict__ col,
                                                      int* __restrict__ s) {
    __shared__ unsigned W[16 * 256];
    int tid  = threadIdx.x;
    int wave = tid >> 6, lane = tid & 63;
    int e = blockIdx.x * ARW_TILE + tid;
    int r = row[e], cv = col[e];
    int b = r >> 9;
    W[tid] = 0; W[tid + 1024] = 0; W[tid + 2048] = 0; W[tid + 3072] = 0;
    __syncthreads();
    unsigned long long mask = ~0ULL;
    #pragma unroll
    for (int bit = 0; bit < 8; bit++) {
        unsigned long long bal = __ballot((b >> bit) & 1);
        mask &= ((b >> bit) & 1) ? bal : ~bal;
    }
    int rankw = __popcll(mask & ((1ULL << lane) - 1ULL));
    W[wave * 256 + b] = (unsigned)__popcll(mask);
    __syncthreads();
    int cross = 0;
    for (int w2 = 0; w2 < 16; w2++) {
        if (w2 >= wave) break;
        cross += (int)W[w2 * 256 + b];
    }
    int base = s[ARW_BT + b * ARW_TP + blockIdx.x];
    s[ARW_P + base + cross + rankw] = ((r & 511) << 17) | cv;   // pack(local_r, col)
}

// ---------- 4. per-bucket stable scatter -> col_s + packed pd ----------
// (R1's proven ballot multisplit.)
__global__ __launch_bounds__(1024) void arw16896_pass2(int* __restrict__ s) {
    __shared__ unsigned W[16 * 512];          // 32 KB
    __shared__ int hist[512], pref[512], runc[512];
    int tid = threadIdx.x, lane = tid & 63, wave = tid >> 6;
    int b = blockIdx.x;
    int start = s[ARW_BT + b * ARW_TP];
    int end   = (b == ARW_NB - 1) ? ARW_N_EDGES : s[ARW_BT + (b + 1) * ARW_TP];
    int cnt = end - start;
    int rows0 = b << 9;
    int nrows = ARW_N_NODES - rows0; if (nrows > 512) nrows = 512;

    // Pass A: histogram
    if (tid < 512) hist[tid] = 0;
    __syncthreads();
    for (int k = tid; k < cnt; k += 1024)
        atomicAdd(&hist[(unsigned)s[ARW_P + start + k] >> 17], 1);
    __syncthreads();
    if (tid < 512) pref[tid] = hist[tid];
    __syncthreads();
    for (int off = 1; off < 512; off <<= 1) {     // inclusive scan of hist
        int x = 0;
        if (tid < 512 && tid >= off) x = pref[tid - off];
        __syncthreads();
        if (tid < 512) pref[tid] += x;
        __syncthreads();
    }
    if (tid < 512) runc[tid] = 0;
    if (tid < nrows) {
        // packed (rowptr<<10 | deg). rowptr < 3.2M (22 bits); deg Poisson(32) << 1023.
        unsigned deg = (unsigned)hist[tid];
        unsigned rp  = (unsigned)(start + pref[tid] - hist[tid]);
        s[ARW_PD + rows0 + tid] = (int)((rp << 10) | deg);
    }
    __syncthreads();

    // Pass B: stable scatter
    for (int c0 = 0; c0 < cnt; c0 += 1024) {
        int k = c0 + tid;
        int valid = (k < cnt) ? 1 : 0;
        unsigned p = valid ? (unsigned)s[ARW_P + start + k] : 0u;
        unsigned lr = p >> 17;                     // 9 bits
        #pragma unroll
        for (int j = 0; j < 8; j++) W[tid + j * 1024] = 0;
        __syncthreads();
        unsigned long long mask = ~0ULL;
        #pragma unroll
        for (int bit = 0; bit < 9; bit++) {
            unsigned long long bal = __ballot((lr >> bit) & 1u);
            mask &= ((lr >> bit) & 1u) ? bal : ~bal;
        }
        mask &= __ballot(valid);
        int rankw = __popcll(mask & ((1ULL << lane) - 1ULL));
        if (valid) W[wave * 512 + lr] = (unsigned)__popcll(mask);
        __syncthreads();
        if (valid) {
            int cross = 0;
            for (int w2 = 0; w2 < 16; w2++) {
                if (w2 >= wave) break;
                cross += (int)W[w2 * 512 + lr];
            }
            int pos = start + (pref[lr] - hist[lr]) + runc[lr] + cross + rankw;
            s[ARW_COLS + pos] = (int)(p & 0x1FFFFu);
        }
        __syncthreads();
        if (tid < 512) {
            int a = 0;
            #pragma unroll
            for (int w = 0; w < 16; w++) a += (int)W[w * 512 + tid];
            runc[tid] += a;
        }
        __syncthreads();
    }
}

// ---------- 5. split col_s -> u16 plane + 1-bit high plane (halves hot footprint) ----------
// Wave reads 64 consecutive cols; ballot packs the 64 high bits into one u64.
__global__ __launch_bounds__(1024) void arw16896_cvt(int* __restrict__ s) {
    int i = blockIdx.x * 1024 + threadIdx.x;     // grid covers exactly N_EDGES
    int lane = threadIdx.x & 63;
    int c = s[ARW_COLS + i];
    ((unsigned short*)(s + ARW_C16))[i] = (unsigned short)c;
    unsigned long long hb = __ballot((c >> 16) & 1);
    if (lane == 0) ((unsigned long long*)(s + ARW_BITS))[i >> 6] = hb;
}

// ---------- 6. walks: 4 walkers/thread; pd (L2) -> {u16, hibit} parallel loads ----------
// Hot random array shrinks 12.8MB -> 6.4MB (+400KB L2-resident bitplane): higher
// per-XCD L2 hit rate -> lower average miss latency. Chain depth per step stays 2;
// the u16 and bit loads are independent (same pos).
__global__ __launch_bounds__(256) void arw16896_walk(const float* __restrict__ ru,
                                                     const int* __restrict__ s,
                                                     float* __restrict__ o) {
    __shared__ float tg[4 * 256 * ARW_LOUT];   // 28 KB: 4 segments of 256x7
    int tid = threadIdx.x;
    int v = blockIdx.x * 256 + tid;
    if (v < ARW_N_NODES) {
        const unsigned short* c16 = (const unsigned short*)(s + ARW_C16);
        const unsigned long long* bp = (const unsigned long long*)(s + ARW_BITS);
        float uu[4][8];
        int cur[4];
        #pragma unroll
        for (int k = 0; k < 4; k++) {
            const float4* rp4 = (const float4*)(ru + (size_t)(v + k * ARW_N_NODES) * 8);
            float4 ra = rp4[0], rb = rp4[1];
            uu[k][0] = ra.x; uu[k][1] = ra.y; uu[k][2] = ra.z; uu[k][3] = ra.w;
            uu[k][4] = rb.x; uu[k][5] = rb.y; uu[k][6] = rb.z; uu[k][7] = rb.w;
        }
        // step 0: all 4 walkers share pd[v]; col loads hit the same row segment
        unsigned pd0 = (unsigned)s[ARW_PD + v];
        int d0  = (int)(pd0 & 1023u);
        int rp0 = (int)(pd0 >> 10);
        #pragma unroll
        for (int k = 0; k < 4; k++) {
            int off = (int)(uu[k][0] * (float)d0);   // f32 mul + trunc == reference
            if (off > d0 - 1) off = d0 - 1;
            int pos = rp0 + off;                     // off=-1 only if d0==0: in-bounds junk
            int nxt = (int)c16[pos] | ((int)((bp[pos >> 6] >> (pos & 63)) & 1ULL) << 16);
            cur[k] = (d0 > 0) ? nxt : v;
        }
        // steps 1..7: 4 independent chains; batch pd loads, then col-plane loads
        #pragma unroll
        for (int t = 1; t < ARW_WLEN; t++) {
            unsigned pdk[4];
            #pragma unroll
            for (int k = 0; k < 4; k++) pdk[k] = (unsigned)s[ARW_PD + cur[k]];
            #pragma unroll
            for (int k = 0; k < 4; k++) {
                int d = (int)(pdk[k] & 1023u);
                int off = (int)(uu[k][t] * (float)d);
                if (off > d - 1) off = d - 1;        // d==0 -> off=-1, loads stay in-bounds
                int pos = (int)(pdk[k] >> 10) + off;
                int nxt = (int)c16[pos] | ((int)((bp[pos >> 6] >> (pos & 63)) & 1ULL) << 16);
                cur[k] = (d > 0) ? nxt : cur[k];
                tg[k * (256 * ARW_LOUT) + tid * ARW_LOUT + (t - 1)] = (float)cur[k];
            }
        }
    }
    __syncthreads();
    int blkN = ARW_N_NODES - blockIdx.x * 256;
    if (blkN > 256) blkN = 256;
    int valid = blkN * ARW_LOUT;
    #pragma unroll
    for (int k = 0; k < 4; k++) {
        int base = ARW_ROW_LEN + ARW_N_EDGES +
                   (k * ARW_N_NODES + blockIdx.x * 256) * ARW_LOUT;
        for (int j = tid; j < valid; j += 256)
            o[base + j] = tg[k * (256 * ARW_LOUT) + j];
    }
}

// ---------- 7. merged assembly: originals + roots + ones (vectorized) ----------
__global__ __launch_bounds__(256) void arw16896_asm(const int* __restrict__ ei,
                                                    const float* __restrict__ wgt,
                                                    float* __restrict__ o) {
    int i4 = blockIdx.x * blockDim.x + threadIdx.x;
    if (i4 < ARW_N_EDGES / 4) {
        int4 r0 = ((const int4*)ei)[i4];
        int4 r1 = ((const int4*)(ei + ARW_N_EDGES))[i4];
        float4 wv = ((const float4*)wgt)[i4];
        ((float4*)o)[i4] = make_float4((float)r0.x, (float)r0.y, (float)r0.z, (float)r0.w);
        ((float4*)(o + ARW_ROW_LEN))[i4] =
            make_float4((float)r1.x, (float)r1.y, (float)r1.z, (float)r1.w);
        ((float4*)(o + 2 * ARW_ROW_LEN))[i4] = wv;
    }
    if (i4 < (ARW_N_WALKERS * ARW_LOUT) / 4) {
        int i = i4 * 4;
        float4 r;
        r.x = (float)(((i    ) / ARW_LOUT) % ARW_N_NODES);
        r.y = (float)(((i + 1) / ARW_LOUT) % ARW_N_NODES);
        r.z = (float)(((i + 2) / ARW_LOUT) % ARW_N_NODES);
        r.w = (float)(((i + 3) / ARW_LOUT) % ARW_N_NODES);
        ((float4*)(o + ARW_N_EDGES))[i4] = r;
        ((float4*)(o + 2 * ARW_ROW_LEN + ARW_N_EDGES))[i4] = make_float4(1.f, 1.f, 1.f, 1.f);
    }
}

extern "C" void kernel_launch(void* const* d_in, const int* in_sizes, int n_in,
                              void* d_out, int out_size, void* d_ws, size_t ws_size,
                              hipStream_t stream) {
    const int*   ei  = (const int*)d_in[0];
    const float* wgt = (const float*)d_in[1];
    const float* ru  = (const float*)d_in[2];
    int*   s = (int*)d_out;
    float* o = (float*)d_out;
    const int* row = ei;
    const int* col = ei + ARW_N_EDGES;

    arw16896_thist <<<ARW_NT / ARW_TPB, 1024, 0, stream>>>(row, s);
    arw16896_btot  <<<ARW_NB, 1024, 0, stream>>>(s);
    arw16896_bbase <<<1, 256, 0, stream>>>(s);
    arw16896_bscan2<<<ARW_NB, 1024, 0, stream>>>(s);
    arw16896_part  <<<ARW_NT, 1024, 0, stream>>>(row, col, s);
    arw16896_pass2 <<<ARW_NB, 1024, 0, stream>>>(s);
    arw16896_cvt   <<<ARW_N_EDGES / 1024, 1024, 0, stream>>>(s);
    arw16896_walk  <<<(ARW_N_NODES + 255) / 256, 256, 0, stream>>>(ru, s, o);
    arw16896_asm   <<<(ARW_N_EDGES / 4 + 255) / 256, 256, 0, stream>>>(ei, wgt, o);
}

// Round 6
// 252.763 us; speedup vs baseline: 2.4968x; 1.0422x over previous
//
#include <hip/hip_runtime.h>

// Problem constants
#define ARW_N_NODES   100000
#define ARW_N_EDGES   3200000
#define ARW_N_WALKERS 400000
#define ARW_WLEN      8
#define ARW_LOUT      7
#define ARW_ROW_LEN   6000000           // N_EDGES + N_WALKERS*LOUT
#define ARW_OUT_ELEMS 18000000          // float32 output elements

// Sort geometry: 256 buckets of 392 rows (b = r/392) -> pass2 runs 1 block/CU.
// 3125 tiles of 1024 edges; thist does 25 tiles/block.
#define ARW_NB    256
#define ARW_RPB   392
#define ARW_NT    3125
#define ARW_TP    3136                 // padded row stride for Ht/Bt (t-contiguous)
#define ARW_TILE  1024
#define ARW_TPB   25                   // tiles per thist block (3125 = 125*25)

// Scratch inside d_out (18M floats = 72MB), int32 view; staged lifetimes:
//   Ht  @ [0, 802816)          histograms Ht[b][t] = HT + b*TP + t
//   Bt  @ [900000, 1702816)    scan bases Bt[b][t]; Bt[b][0] = bucket start
//   tot @ [1750000, +256)      per-bucket totals
//   cb  @ [1760000, +256)      bucket exclusive bases
//   pd  @ [1800000, 1900000)   packed (rowptr<<10 | deg), written by pass2
//   P   @ [6000000, 9200000)   packed partition (row1-orig region, dead after pass2)
//   col_s @ [12000000, 15200000) (weights region; asm overwrites last)
// walk writes float targets @ [9200000, 12000000). asm (last) overwrites all scratch.
#define ARW_HT    0
#define ARW_BT    900000
#define ARW_TOT   1750000
#define ARW_CB    1760000
#define ARW_PD    1800000
#define ARW_P     6000000
#define ARW_COLS  12000000

__global__ void AddRandomWalkEdge_16896401342869_kernel() {}

// ---------- 1. tile histogram, 25 tiles/block (write-allocate-friendly runs) ----------
__global__ __launch_bounds__(1024) void arw16896_thist(const int* __restrict__ row,
                                                       int* __restrict__ s) {
    __shared__ int h[ARW_TPB * 256];
    int tid = threadIdx.x;
    for (int x = tid; x < ARW_TPB * 256; x += 1024) h[x] = 0;
    __syncthreads();
    int base_e = blockIdx.x * (ARW_TPB * ARW_TILE) + tid;
    #pragma unroll
    for (int j = 0; j < ARW_TPB; j++)
        atomicAdd(&h[j * 256 + (row[base_e + j * 1024] / ARW_RPB)], 1);
    __syncthreads();
    for (int x = tid; x < ARW_TPB * ARW_NB; x += 1024) {
        int b = x / ARW_TPB, j = x % ARW_TPB;
        s[ARW_HT + b * ARW_TP + blockIdx.x * ARW_TPB + j] = h[j * 256 + b];
    }
}

// ---------- 2a. per-bucket totals (256 blocks, 1024 thr, shuffle reduce) ----------
__global__ __launch_bounds__(1024) void arw16896_btot(int* __restrict__ s) {
    __shared__ int wsum[16];
    int b = blockIdx.x, tid = threadIdx.x, lane = tid & 63, wid = tid >> 6;
    int acc = 0;
    for (int t = tid; t < ARW_NT; t += 1024) acc += s[ARW_HT + b * ARW_TP + t];
    #pragma unroll
    for (int off = 32; off > 0; off >>= 1) acc += __shfl_down(acc, off, 64);
    if (lane == 0) wsum[wid] = acc;
    __syncthreads();
    if (tid == 0) {
        int a = 0;
        #pragma unroll
        for (int w = 0; w < 16; w++) a += wsum[w];
        s[ARW_TOT + b] = a;
    }
}

// ---------- 2b. exclusive scan of 256 bucket totals (1 block) ----------
__global__ __launch_bounds__(256) void arw16896_bbase(int* __restrict__ s) {
    __shared__ int sm[256];
    int tid = threadIdx.x;
    int v = s[ARW_TOT + tid];
    sm[tid] = v;
    __syncthreads();
    for (int off = 1; off < 256; off <<= 1) {
        int x = 0;
        if (tid >= off) x = sm[tid - off];
        __syncthreads();
        sm[tid] += x;
        __syncthreads();
    }
    s[ARW_CB + tid] = sm[tid] - v;
}

// ---------- 2c. per-bucket chunked exclusive scan -> Bt[b][t] (shuffle) ----------
__global__ __launch_bounds__(1024) void arw16896_bscan2(int* __restrict__ s) {
    __shared__ int wsum[16];
    int b = blockIdx.x, tid = threadIdx.x, lane = tid & 63, wid = tid >> 6;
    int carry = s[ARW_CB + b];
    for (int c0 = 0; c0 < ARW_NT; c0 += 1024) {
        int t = c0 + tid;
        int v = (t < ARW_NT) ? s[ARW_HT + b * ARW_TP + t] : 0;
        int sv = v;
        #pragma unroll
        for (int off = 1; off < 64; off <<= 1) {
            int x = __shfl_up(sv, off, 64);
            if (lane >= off) sv += x;
        }
        if (lane == 63) wsum[wid] = sv;
        __syncthreads();
        int pre = 0, tot = 0;
        #pragma unroll
        for (int w = 0; w < 16; w++) {
            int x = wsum[w];
            if (w < wid) pre += x;
            tot += x;
        }
        if (t < ARW_NT) s[ARW_BT + b * ARW_TP + t] = carry + pre + sv - v;
        carry += tot;
        __syncthreads();
    }
}

// ---------- 3. stable partition into buckets (ballot multisplit, no atomics) ----------
__global__ __launch_bounds__(1024) void arw16896_part(const int* __restrict__ row,
                                                      const int* __restrict__ col,
                                                      int* __restrict__ s) {
    __shared__ unsigned W[16 * 256];
    int tid  = threadIdx.x;
    int wave = tid >> 6, lane = tid & 63;
    int e = blockIdx.x * ARW_TILE + tid;
    int r = row[e], cv = col[e];
    int b = r / ARW_RPB;                 // magic-mul division
    int lr = r - b * ARW_RPB;            // 9 bits (<392)
    W[tid] = 0; W[tid + 1024] = 0; W[tid + 2048] = 0; W[tid + 3072] = 0;
    __syncthreads();
    unsigned long long mask = ~0ULL;
    #pragma unroll
    for (int bit = 0; bit < 8; bit++) {
        unsigned long long bal = __ballot((b >> bit) & 1);
        mask &= ((b >> bit) & 1) ? bal : ~bal;
    }
    int rankw = __popcll(mask & ((1ULL << lane) - 1ULL));
    W[wave * 256 + b] = (unsigned)__popcll(mask);
    __syncthreads();
    int cross = 0;
    for (int w2 = 0; w2 < 16; w2++) {
        if (w2 >= wave) break;
        cross += (int)W[w2 * 256 + b];
    }
    int base = s[ARW_BT + b * ARW_TP + blockIdx.x];
    s[ARW_P + base + cross + rankw] = (lr << 17) | cv;   // pack(local_r, col)
}

// ---------- 4. per-bucket stable scatter -> col_s + packed pd ----------
// Ballot multisplit (proven R1 structure); now 256 buckets = exactly 1 block/CU.
__global__ __launch_bounds__(1024) void arw16896_pass2(int* __restrict__ s) {
    __shared__ unsigned W[16 * 512];          // 32 KB
    __shared__ int hist[512], pref[512], runc[512];
    int tid = threadIdx.x, lane = tid & 63, wave = tid >> 6;
    int b = blockIdx.x;
    int start = s[ARW_BT + b * ARW_TP];
    int end   = (b == ARW_NB - 1) ? ARW_N_EDGES : s[ARW_BT + (b + 1) * ARW_TP];
    int cnt = end - start;
    int rows0 = b * ARW_RPB;
    int nrows = ARW_N_NODES - rows0; if (nrows > ARW_RPB) nrows = ARW_RPB;

    // Pass A: histogram
    if (tid < 512) hist[tid] = 0;
    __syncthreads();
    for (int k = tid; k < cnt; k += 1024)
        atomicAdd(&hist[(unsigned)s[ARW_P + start + k] >> 17], 1);
    __syncthreads();
    if (tid < 512) pref[tid] = hist[tid];
    __syncthreads();
    for (int off = 1; off < 512; off <<= 1) {     // inclusive scan of hist
        int x = 0;
        if (tid < 512 && tid >= off) x = pref[tid - off];
        __syncthreads();
        if (tid < 512) pref[tid] += x;
        __syncthreads();
    }
    if (tid < 512) runc[tid] = 0;
    if (tid < nrows) {
        // packed (rowptr<<10 | deg). rowptr < 3.2M (22 bits); deg Poisson(32) << 1023.
        unsigned deg = (unsigned)hist[tid];
        unsigned rp  = (unsigned)(start + pref[tid] - hist[tid]);
        s[ARW_PD + rows0 + tid] = (int)((rp << 10) | deg);
    }
    __syncthreads();

    // Pass B: stable scatter
    for (int c0 = 0; c0 < cnt; c0 += 1024) {
        int k = c0 + tid;
        int valid = (k < cnt) ? 1 : 0;
        unsigned p = valid ? (unsigned)s[ARW_P + start + k] : 0u;
        unsigned lr = p >> 17;                     // 9 bits
        #pragma unroll
        for (int j = 0; j < 8; j++) W[tid + j * 1024] = 0;
        __syncthreads();
        unsigned long long mask = ~0ULL;
        #pragma unroll
        for (int bit = 0; bit < 9; bit++) {
            unsigned long long bal = __ballot((lr >> bit) & 1u);
            mask &= ((lr >> bit) & 1u) ? bal : ~bal;
        }
        mask &= __ballot(valid);
        int rankw = __popcll(mask & ((1ULL << lane) - 1ULL));
        if (valid) W[wave * 512 + lr] = (unsigned)__popcll(mask);
        __syncthreads();
        if (valid) {
            int cross = 0;
            for (int w2 = 0; w2 < 16; w2++) {
                if (w2 >= wave) break;
                cross += (int)W[w2 * 512 + lr];
            }
            int pos = start + (pref[lr] - hist[lr]) + runc[lr] + cross + rankw;
            s[ARW_COLS + pos] = (int)(p & 0x1FFFFu);
        }
        __syncthreads();
        if (tid < 512) {
            int a = 0;
            #pragma unroll
            for (int w = 0; w < 16; w++) a += (int)W[w * 512 + tid];
            runc[tid] += a;
        }
        __syncthreads();
    }
}

// ---------- 5. walks: 4 walkers/thread, 64-thread blocks for per-CU balance ----------
// MSHR-saturated per CU: time ~ per-CU miss count. 256-thread blocks gave 1-vs-2
// blocks/CU (1.31x makespan skew); 64-thread blocks give 6-vs-7 (1.15x).
__global__ __launch_bounds__(64) void arw16896_walk(const float* __restrict__ ru,
                                                    const int* __restrict__ s,
                                                    float* __restrict__ o) {
    __shared__ float tg[4 * 64 * ARW_LOUT];    // 7 KB: 4 segments of 64x7
    int tid = threadIdx.x;
    int v = blockIdx.x * 64 + tid;
    if (v < ARW_N_NODES) {
        float uu[4][8];
        int cur[4];
        #pragma unroll
        for (int k = 0; k < 4; k++) {
            const float4* rp4 = (const float4*)(ru + (size_t)(v + k * ARW_N_NODES) * 8);
            float4 ra = rp4[0], rb = rp4[1];
            uu[k][0] = ra.x; uu[k][1] = ra.y; uu[k][2] = ra.z; uu[k][3] = ra.w;
            uu[k][4] = rb.x; uu[k][5] = rb.y; uu[k][6] = rb.z; uu[k][7] = rb.w;
        }
        // step 0: all 4 walkers share pd[v]; col loads hit the same row segment
        unsigned pd0 = (unsigned)s[ARW_PD + v];
        int d0  = (int)(pd0 & 1023u);
        int rp0 = (int)(pd0 >> 10);
        #pragma unroll
        for (int k = 0; k < 4; k++) {
            int off = (int)(uu[k][0] * (float)d0);   // f32 mul + trunc == reference
            if (off > d0 - 1) off = d0 - 1;
            int nxt = s[ARW_COLS + rp0 + off];       // off=-1 only if d0==0: in-bounds junk
            cur[k] = (d0 > 0) ? nxt : v;
        }
        // steps 1..7: 4 independent chains; batch the 4 pd loads, then 4 col loads
        #pragma unroll
        for (int t = 1; t < ARW_WLEN; t++) {
            unsigned pdk[4];
            #pragma unroll
            for (int k = 0; k < 4; k++) pdk[k] = (unsigned)s[ARW_PD + cur[k]];
            #pragma unroll
            for (int k = 0; k < 4; k++) {
                int d = (int)(pdk[k] & 1023u);
                int off = (int)(uu[k][t] * (float)d);
                if (off > d - 1) off = d - 1;        // d==0 -> off=-1, load stays in-bounds
                int nxt = s[ARW_COLS + (int)(pdk[k] >> 10) + off];
                cur[k] = (d > 0) ? nxt : cur[k];
                tg[k * (64 * ARW_LOUT) + tid * ARW_LOUT + (t - 1)] = (float)cur[k];
            }
        }
    }
    __syncthreads();
    int blkN = ARW_N_NODES - blockIdx.x * 64;
    if (blkN > 64) blkN = 64;
    int valid = blkN * ARW_LOUT;
    #pragma unroll
    for (int k = 0; k < 4; k++) {
        int base = ARW_ROW_LEN + ARW_N_EDGES +
                   (k * ARW_N_NODES + blockIdx.x * 64) * ARW_LOUT;
        for (int j = tid; j < valid; j += 64)
            o[base + j] = tg[k * (64 * ARW_LOUT) + j];
    }
}

// ---------- 6. merged assembly: originals + roots + ones (vectorized) ----------
__global__ __launch_bounds__(256) void arw16896_asm(const int* __restrict__ ei,
                                                    const float* __restrict__ wgt,
                                                    float* __restrict__ o) {
    int i4 = blockIdx.x * blockDim.x + threadIdx.x;
    if (i4 < ARW_N_EDGES / 4) {
        int4 r0 = ((const int4*)ei)[i4];
        int4 r1 = ((const int4*)(ei + ARW_N_EDGES))[i4];
        float4 wv = ((const float4*)wgt)[i4];
        ((float4*)o)[i4] = make_float4((float)r0.x, (float)r0.y, (float)r0.z, (float)r0.w);
        ((float4*)(o + ARW_ROW_LEN))[i4] =
            make_float4((float)r1.x, (float)r1.y, (float)r1.z, (float)r1.w);
        ((float4*)(o + 2 * ARW_ROW_LEN))[i4] = wv;
    }
    if (i4 < (ARW_N_WALKERS * ARW_LOUT) / 4) {
        int i = i4 * 4;
        float4 r;
        r.x = (float)(((i    ) / ARW_LOUT) % ARW_N_NODES);
        r.y = (float)(((i + 1) / ARW_LOUT) % ARW_N_NODES);
        r.z = (float)(((i + 2) / ARW_LOUT) % ARW_N_NODES);
        r.w = (float)(((i + 3) / ARW_LOUT) % ARW_N_NODES);
        ((float4*)(o + ARW_N_EDGES))[i4] = r;
        ((float4*)(o + 2 * ARW_ROW_LEN + ARW_N_EDGES))[i4] = make_float4(1.f, 1.f, 1.f, 1.f);
    }
}

extern "C" void kernel_launch(void* const* d_in, const int* in_sizes, int n_in,
                              void* d_out, int out_size, void* d_ws, size_t ws_size,
                              hipStream_t stream) {
    const int*   ei  = (const int*)d_in[0];
    const float* wgt = (const float*)d_in[1];
    const float* ru  = (const float*)d_in[2];
    int*   s = (int*)d_out;
    float* o = (float*)d_out;
    const int* row = ei;
    const int* col = ei + ARW_N_EDGES;

    arw16896_thist <<<ARW_NT / ARW_TPB, 1024, 0, stream>>>(row, s);
    arw16896_btot  <<<ARW_NB, 1024, 0, stream>>>(s);
    arw16896_bbase <<<1, 256, 0, stream>>>(s);
    arw16896_bscan2<<<ARW_NB, 1024, 0, stream>>>(s);
    arw16896_part  <<<ARW_NT, 1024, 0, stream>>>(row, col, s);
    arw16896_pass2 <<<ARW_NB, 1024, 0, stream>>>(s);
    arw16896_walk  <<<(ARW_N_NODES + 63) / 64, 64, 0, stream>>>(ru, s, o);
    arw16896_asm   <<<(ARW_N_EDGES / 4 + 255) / 256, 256, 0, stream>>>(ei, wgt, o);
}

// Round 7
// 234.771 us; speedup vs baseline: 2.6881x; 1.0766x over previous
//
#include <hip/hip_runtime.h>

// Problem constants
#define ARW_N_NODES   100000
#define ARW_N_EDGES   3200000
#define ARW_N_WALKERS 400000
#define ARW_WLEN      8
#define ARW_LOUT      7
#define ARW_ROW_LEN   6000000           // N_EDGES + N_WALKERS*LOUT
#define ARW_OUT_ELEMS 18000000          // float32 output elements

// Sort geometry: 256 buckets of 392 rows (b = r/392); 3125 tiles of 1024 edges;
// thist does 5 tiles/block (625 blocks: full CU coverage + short write runs).
#define ARW_NB    256
#define ARW_RPB   392
#define ARW_NT    3125
#define ARW_TP    3136                 // padded row stride for Ht/Bt (t-contiguous)
#define ARW_TILE  1024
#define ARW_TPB   5                    // tiles per thist block (3125 = 625*5)
#define ARW_PMAX  14336                // pass2 LDS P-stage capacity (bucket max ~13.0K)

// Scratch inside d_out (18M floats = 72MB), int32 view; staged lifetimes:
//   Ht  @ [0, 802816)          histograms Ht[b][t] = HT + b*TP + t
//   Bt  @ [900000, 1702816)    bucket-LOCAL scan bases Bt[b][t] (exclusive, from 0)
//   tot @ [1750000, +256)      per-bucket totals (emitted by bscan2)
//   cb  @ [1760000, +256)      bucket exclusive bases (global)
//   pd  @ [1800000, 1900000)   packed (rowptr<<10 | deg), written by pass2
//   P   @ [6000000, 9200000)   packed partition (dead after pass2; walk's fused
//                              row1-copy overwrites it)
//   col_s @ [12000000, 15200000) (weights region; asm overwrites after walk)
// walk writes: targets [9200000,12000000), roots [3200000,6000000),
//              row1-originals [6000000,9200000).
// asm (last) writes [0,3200000) + [12000000,18000000).
#define ARW_HT    0
#define ARW_BT    900000
#define ARW_TOT   1750000
#define ARW_CB    1760000
#define ARW_PD    1800000
#define ARW_P     6000000
#define ARW_COLS  12000000

__global__ void AddRandomWalkEdge_16896401342869_kernel() {}

// ---------- 1. tile histogram, 5 tiles/block ----------
// 625 blocks (>=256 CUs busy, unlike TPB=25's 125); writes 5-int runs per bucket
// (write-allocate ~10MB, vs 39MB at TPB=1).
__global__ __launch_bounds__(1024) void arw16896_thist(const int* __restrict__ row,
                                                       int* __restrict__ s) {
    __shared__ int h[ARW_TPB * 256];
    int tid = threadIdx.x;
    for (int x = tid; x < ARW_TPB * 256; x += 1024) h[x] = 0;
    __syncthreads();
    int base_e = blockIdx.x * (ARW_TPB * ARW_TILE) + tid;
    #pragma unroll
    for (int j = 0; j < ARW_TPB; j++)
        atomicAdd(&h[j * 256 + (row[base_e + j * 1024] / ARW_RPB)], 1);
    __syncthreads();
    for (int x = tid; x < ARW_TPB * ARW_NB; x += 1024) {
        int b = x / ARW_TPB, j = x % ARW_TPB;
        s[ARW_HT + b * ARW_TP + blockIdx.x * ARW_TPB + j] = h[j * 256 + b];
    }
}

// ---------- 2a. per-bucket chunked exclusive scan (local, from 0) + total ----------
// Replaces btot+old bscan2: Bt[b][t] is now bucket-local; total -> tot[b].
__global__ __launch_bounds__(1024) void arw16896_bscan2(int* __restrict__ s) {
    __shared__ int wsum[16];
    int b = blockIdx.x, tid = threadIdx.x, lane = tid & 63, wid = tid >> 6;
    int carry = 0;
    for (int c0 = 0; c0 < ARW_NT; c0 += 1024) {
        int t = c0 + tid;
        int v = (t < ARW_NT) ? s[ARW_HT + b * ARW_TP + t] : 0;
        int sv = v;
        #pragma unroll
        for (int off = 1; off < 64; off <<= 1) {
            int x = __shfl_up(sv, off, 64);
            if (lane >= off) sv += x;
        }
        if (lane == 63) wsum[wid] = sv;
        __syncthreads();
        int pre = 0, tot = 0;
        #pragma unroll
        for (int w = 0; w < 16; w++) {
            int x = wsum[w];
            if (w < wid) pre += x;
            tot += x;
        }
        if (t < ARW_NT) s[ARW_BT + b * ARW_TP + t] = carry + pre + sv - v;
        carry += tot;
        __syncthreads();
    }
    if (tid == 0) s[ARW_TOT + b] = carry;
}

// ---------- 2b. exclusive scan of 256 bucket totals (1 block) -> cb ----------
__global__ __launch_bounds__(256) void arw16896_bbase(int* __restrict__ s) {
    __shared__ int sm[256];
    int tid = threadIdx.x;
    int v = s[ARW_TOT + tid];
    sm[tid] = v;
    __syncthreads();
    for (int off = 1; off < 256; off <<= 1) {
        int x = 0;
        if (tid >= off) x = sm[tid - off];
        __syncthreads();
        sm[tid] += x;
        __syncthreads();
    }
    s[ARW_CB + tid] = sm[tid] - v;
}

// ---------- 3. stable partition into buckets (ballot multisplit, no atomics) ----------
__global__ __launch_bounds__(1024) void arw16896_part(const int* __restrict__ row,
                                                      const int* __restrict__ col,
                                                      int* __restrict__ s) {
    __shared__ unsigned W[16 * 256];
    int tid  = threadIdx.x;
    int wave = tid >> 6, lane = tid & 63;
    int e = blockIdx.x * ARW_TILE + tid;
    int r = row[e], cv = col[e];
    int b = r / ARW_RPB;                 // magic-mul division
    int lr = r - b * ARW_RPB;            // 9 bits (<392)
    W[tid] = 0; W[tid + 1024] = 0; W[tid + 2048] = 0; W[tid + 3072] = 0;
    __syncthreads();
    unsigned long long mask = ~0ULL;
    #pragma unroll
    for (int bit = 0; bit < 8; bit++) {
        unsigned long long bal = __ballot((b >> bit) & 1);
        mask &= ((b >> bit) & 1) ? bal : ~bal;
    }
    int rankw = __popcll(mask & ((1ULL << lane) - 1ULL));
    W[wave * 256 + b] = (unsigned)__popcll(mask);
    __syncthreads();
    int cross = 0;
    for (int w2 = 0; w2 < 16; w2++) {
        if (w2 >= wave) break;
        cross += (int)W[w2 * 256 + b];
    }
    int base = s[ARW_CB + b] + s[ARW_BT + b * ARW_TP + blockIdx.x];
    s[ARW_P + base + cross + rankw] = (lr << 17) | cv;   // pack(local_r, col)
}

// ---------- 4. per-bucket stable scatter -> col_s + packed pd ----------
// Ballot multisplit; bucket's P window (<=56KB) staged in LDS once (kills the
// second 12.8MB global read). W shrunk to ushort (wave counts <= 64).
__global__ __launch_bounds__(1024) void arw16896_pass2(int* __restrict__ s) {
    __shared__ int PL[ARW_PMAX];              // 56 KB
    __shared__ unsigned short W[16 * 512];    // 16 KB
    __shared__ int hist[512], pref[512], runc[512];
    int tid = threadIdx.x, lane = tid & 63, wave = tid >> 6;
    int b = blockIdx.x;
    int start = s[ARW_CB + b];
    int end   = (b == ARW_NB - 1) ? ARW_N_EDGES : s[ARW_CB + b + 1];
    int cnt = end - start;
    int staged = cnt < ARW_PMAX ? cnt : ARW_PMAX;   // overflow ~16 sigma; guarded
    int rows0 = b * ARW_RPB;
    int nrows = ARW_N_NODES - rows0; if (nrows > ARW_RPB) nrows = ARW_RPB;

    for (int k = tid; k < staged; k += 1024) PL[k] = s[ARW_P + start + k];
    if (tid < 512) hist[tid] = 0;
    __syncthreads();

    // Pass A: histogram (from LDS)
    for (int k = tid; k < cnt; k += 1024) {
        unsigned p = (unsigned)(k < staged ? PL[k] : s[ARW_P + start + k]);
        atomicAdd(&hist[p >> 17], 1);
    }
    __syncthreads();
    if (tid < 512) pref[tid] = hist[tid];
    __syncthreads();
    for (int off = 1; off < 512; off <<= 1) {     // inclusive scan of hist
        int x = 0;
        if (tid < 512 && tid >= off) x = pref[tid - off];
        __syncthreads();
        if (tid < 512) pref[tid] += x;
        __syncthreads();
    }
    if (tid < 512) runc[tid] = 0;
    if (tid < nrows) {
        // packed (rowptr<<10 | deg). rowptr < 3.2M (22 bits); deg Poisson(32) << 1023.
        unsigned deg = (unsigned)hist[tid];
        unsigned rp  = (unsigned)(start + pref[tid] - hist[tid]);
        s[ARW_PD + rows0 + tid] = (int)((rp << 10) | deg);
    }
    __syncthreads();

    // Pass B: stable scatter (reads LDS)
    for (int c0 = 0; c0 < cnt; c0 += 1024) {
        int k = c0 + tid;
        int valid = (k < cnt) ? 1 : 0;
        unsigned p = 0u;
        if (valid) p = (unsigned)(k < staged ? PL[k] : s[ARW_P + start + k]);
        unsigned lr = p >> 17;                     // 9 bits
        #pragma unroll
        for (int j = 0; j < 8; j++) W[tid + j * 1024] = 0;
        __syncthreads();
        unsigned long long mask = ~0ULL;
        #pragma unroll
        for (int bit = 0; bit < 9; bit++) {
            unsigned long long bal = __ballot((lr >> bit) & 1u);
            mask &= ((lr >> bit) & 1u) ? bal : ~bal;
        }
        mask &= __ballot(valid);
        int rankw = __popcll(mask & ((1ULL << lane) - 1ULL));
        if (valid) W[wave * 512 + lr] = (unsigned short)__popcll(mask);
        __syncthreads();
        if (valid) {
            int cross = 0;
            for (int w2 = 0; w2 < 16; w2++) {
                if (w2 >= wave) break;
                cross += (int)W[w2 * 512 + lr];
            }
            int pos = start + (pref[lr] - hist[lr]) + runc[lr] + cross + rankw;
            s[ARW_COLS + pos] = (int)(p & 0x1FFFFu);
        }
        __syncthreads();
        if (tid < 512) {
            int a = 0;
            #pragma unroll
            for (int w = 0; w < 16; w++) a += (int)W[w * 512 + tid];
            runc[tid] += a;
        }
        __syncthreads();
    }
}

// ---------- 5. walks (256 thr, proven-best) + fused streaming tail ----------
// Walk is miss-throughput bound at ~36% HBM BW, VALU 3%: the idle BW absorbs
// the row1-originals copy ([6M,9.2M), over dead P) and the roots fill
// ([3.2M,6M), empty scratch). Neither conflicts with walk's reads (pd@1.8M,
// col_s@12M) or writes (targets@9.2M).
__global__ __launch_bounds__(256) void arw16896_walk(const float* __restrict__ ru,
                                                     const int* __restrict__ ei,
                                                     const int* __restrict__ s,
                                                     float* __restrict__ o) {
    __shared__ float tg[4 * 256 * ARW_LOUT];   // 28 KB: 4 segments of 256x7
    int tid = threadIdx.x;
    int v = blockIdx.x * 256 + tid;
    if (v < ARW_N_NODES) {
        float uu[4][8];
        int cur[4];
        #pragma unroll
        for (int k = 0; k < 4; k++) {
            const float4* rp4 = (const float4*)(ru + (size_t)(v + k * ARW_N_NODES) * 8);
            float4 ra = rp4[0], rb = rp4[1];
            uu[k][0] = ra.x; uu[k][1] = ra.y; uu[k][2] = ra.z; uu[k][3] = ra.w;
            uu[k][4] = rb.x; uu[k][5] = rb.y; uu[k][6] = rb.z; uu[k][7] = rb.w;
        }
        // step 0: all 4 walkers share pd[v]; col loads hit the same row segment
        unsigned pd0 = (unsigned)s[ARW_PD + v];
        int d0  = (int)(pd0 & 1023u);
        int rp0 = (int)(pd0 >> 10);
        #pragma unroll
        for (int k = 0; k < 4; k++) {
            int off = (int)(uu[k][0] * (float)d0);   // f32 mul + trunc == reference
            if (off > d0 - 1) off = d0 - 1;
            int nxt = s[ARW_COLS + rp0 + off];       // off=-1 only if d0==0: in-bounds junk
            cur[k] = (d0 > 0) ? nxt : v;
        }
        // steps 1..7: 4 independent chains; batch the 4 pd loads, then 4 col loads
        #pragma unroll
        for (int t = 1; t < ARW_WLEN; t++) {
            unsigned pdk[4];
            #pragma unroll
            for (int k = 0; k < 4; k++) pdk[k] = (unsigned)s[ARW_PD + cur[k]];
            #pragma unroll
            for (int k = 0; k < 4; k++) {
                int d = (int)(pdk[k] & 1023u);
                int off = (int)(uu[k][t] * (float)d);
                if (off > d - 1) off = d - 1;        // d==0 -> off=-1, load stays in-bounds
                int nxt = s[ARW_COLS + (int)(pdk[k] >> 10) + off];
                cur[k] = (d > 0) ? nxt : cur[k];
                tg[k * (256 * ARW_LOUT) + tid * ARW_LOUT + (t - 1)] = (float)cur[k];
            }
        }
    }
    __syncthreads();
    int blkN = ARW_N_NODES - blockIdx.x * 256;
    if (blkN > 256) blkN = 256;
    int valid = blkN * ARW_LOUT;
    #pragma unroll
    for (int k = 0; k < 4; k++) {
        int base = ARW_ROW_LEN + ARW_N_EDGES +
                   (k * ARW_N_NODES + blockIdx.x * 256) * ARW_LOUT;
        for (int j = tid; j < valid; j += 256)
            o[base + j] = tg[k * (256 * ARW_LOUT) + j];
    }
    // fused streaming tail (grid-stride over all walk threads)
    int gid = blockIdx.x * 256 + tid;
    int stride = gridDim.x * 256;
    for (int i4 = gid; i4 < ARW_N_EDGES / 4; i4 += stride) {
        int4 r1 = ((const int4*)(ei + ARW_N_EDGES))[i4];
        ((float4*)(o + ARW_ROW_LEN))[i4] =
            make_float4((float)r1.x, (float)r1.y, (float)r1.z, (float)r1.w);
    }
    for (int i4 = gid; i4 < (ARW_N_WALKERS * ARW_LOUT) / 4; i4 += stride) {
        int i = i4 * 4;
        float4 r;
        r.x = (float)(((i    ) / ARW_LOUT) % ARW_N_NODES);
        r.y = (float)(((i + 1) / ARW_LOUT) % ARW_N_NODES);
        r.z = (float)(((i + 2) / ARW_LOUT) % ARW_N_NODES);
        r.w = (float)(((i + 3) / ARW_LOUT) % ARW_N_NODES);
        ((float4*)(o + ARW_N_EDGES))[i4] = r;
    }
}

// ---------- 6. remaining assembly: row0 originals + weights + ones ----------
__global__ __launch_bounds__(256) void arw16896_asm(const int* __restrict__ ei,
                                                    const float* __restrict__ wgt,
                                                    float* __restrict__ o) {
    int i4 = blockIdx.x * blockDim.x + threadIdx.x;
    if (i4 < ARW_N_EDGES / 4) {
        int4 r0 = ((const int4*)ei)[i4];
        float4 wv = ((const float4*)wgt)[i4];
        ((float4*)o)[i4] = make_float4((float)r0.x, (float)r0.y, (float)r0.z, (float)r0.w);
        ((float4*)(o + 2 * ARW_ROW_LEN))[i4] = wv;
    }
    if (i4 < (ARW_N_WALKERS * ARW_LOUT) / 4) {
        ((float4*)(o + 2 * ARW_ROW_LEN + ARW_N_EDGES))[i4] = make_float4(1.f, 1.f, 1.f, 1.f);
    }
}

extern "C" void kernel_launch(void* const* d_in, const int* in_sizes, int n_in,
                              void* d_out, int out_size, void* d_ws, size_t ws_size,
                              hipStream_t stream) {
    const int*   ei  = (const int*)d_in[0];
    const float* wgt = (const float*)d_in[1];
    const float* ru  = (const float*)d_in[2];
    int*   s = (int*)d_out;
    float* o = (float*)d_out;
    const int* row = ei;
    const int* col = ei + ARW_N_EDGES;

    arw16896_thist <<<ARW_NT / ARW_TPB, 1024, 0, stream>>>(row, s);
    arw16896_bscan2<<<ARW_NB, 1024, 0, stream>>>(s);
    arw16896_bbase <<<1, 256, 0, stream>>>(s);
    arw16896_part  <<<ARW_NT, 1024, 0, stream>>>(row, col, s);
    arw16896_pass2 <<<ARW_NB, 1024, 0, stream>>>(s);
    arw16896_walk  <<<(ARW_N_NODES + 255) / 256, 256, 0, stream>>>(ru, ei, s, o);
    arw16896_asm   <<<(ARW_N_EDGES / 4 + 255) / 256, 256, 0, stream>>>(ei, wgt, o);
}